// Round 11
// baseline (286.989 us; speedup 1.0000x reference)
//
#include <hip/hip_runtime.h>
#include <hip/hip_bf16.h>

typedef unsigned short u16;
typedef unsigned int u32;
typedef __bf16 bf16x8 __attribute__((ext_vector_type(8)));
typedef float f32x4 __attribute__((ext_vector_type(4)));
typedef int i32x4 __attribute__((ext_vector_type(4)));
typedef u16 u16x4 __attribute__((ext_vector_type(4)));
typedef u16 u16x8 __attribute__((ext_vector_type(8)));

#define D_IN 4096
#define D_OUT 4096
#define M_TOT 8192
#define RANK_ 16

#define BM 256
#define BN 256
#define BK 64
#define NT (D_IN / BK)   // 64 K-tiles
#define OPB 2            // dequant rows per block

__device__ __forceinline__ u16 f2bf(float f) {
    union { float f; u32 u; } v; v.f = f;
    u32 u = v.u;
    u32 r = (u + 0x7FFFu + ((u >> 16) & 1u)) >> 16;  // round-to-nearest-even
    return (u16)r;
}

// W_eff[o,i] = q[o,i]*scale[o] + min[o] + 2*sum_r B[o,r]*A[r,i]  -> bf16
__global__ __launch_bounds__(256) void dequant_fold_kernel(
        const int* __restrict__ q, const float* __restrict__ wmin,
        const float* __restrict__ wscale, const float* __restrict__ A,
        const float* __restrict__ Bm, u16* __restrict__ Wb) {
    const int K = D_IN;
    int o0 = blockIdx.x * OPB;
    float s0 = wscale[o0], s1 = wscale[o0 + 1];
    float m0 = wmin[o0],   m1 = wmin[o0 + 1];
    float Br0[RANK_], Br1[RANK_];   // block-uniform -> SGPRs
    #pragma unroll
    for (int r = 0; r < RANK_; ++r) {
        Br0[r] = 2.0f * Bm[(size_t)o0 * RANK_ + r];
        Br1[r] = 2.0f * Bm[(size_t)(o0 + 1) * RANK_ + r];
    }
    for (int i4 = threadIdx.x; i4 < K / 4; i4 += 256) {
        int i = i4 * 4;
        i32x4 q0 = __builtin_nontemporal_load((const i32x4*)(q + (size_t)o0 * K + i));
        i32x4 q1 = __builtin_nontemporal_load((const i32x4*)(q + (size_t)(o0 + 1) * K + i));
        float v00 = (float)q0.x * s0 + m0, v01 = (float)q0.y * s0 + m0;
        float v02 = (float)q0.z * s0 + m0, v03 = (float)q0.w * s0 + m0;
        float v10 = (float)q1.x * s1 + m1, v11 = (float)q1.y * s1 + m1;
        float v12 = (float)q1.z * s1 + m1, v13 = (float)q1.w * s1 + m1;
        #pragma unroll
        for (int r = 0; r < RANK_; ++r) {
            f32x4 av = *(const f32x4*)(A + (size_t)r * K + i);
            v00 += Br0[r] * av.x; v01 += Br0[r] * av.y;
            v02 += Br0[r] * av.z; v03 += Br0[r] * av.w;
            v10 += Br1[r] * av.x; v11 += Br1[r] * av.y;
            v12 += Br1[r] * av.z; v13 += Br1[r] * av.w;
        }
        u16x4 o0v, o1v;
        o0v.x = f2bf(v00); o0v.y = f2bf(v01); o0v.z = f2bf(v02); o0v.w = f2bf(v03);
        o1v.x = f2bf(v10); o1v.y = f2bf(v11); o1v.z = f2bf(v12); o1v.w = f2bf(v13);
        *(u16x4*)(Wb + (size_t)o0 * K + i) = o0v;
        *(u16x4*)(Wb + (size_t)(o0 + 1) * K + i) = o1v;
    }
}

// fp32 -> bf16, 8 elems/thread; x is single-pass -> non-temporal load
__global__ void xcast_kernel(const float* __restrict__ x, u16* __restrict__ xb) {
    size_t i = (size_t)blockIdx.x * blockDim.x + threadIdx.x;
    const f32x4* p = (const f32x4*)x + i * 2;
    f32x4 a = __builtin_nontemporal_load(p);
    f32x4 b = __builtin_nontemporal_load(p + 1);
    u16x8 o;
    o[0] = f2bf(a.x); o[1] = f2bf(a.y); o[2] = f2bf(a.z); o[3] = f2bf(a.w);
    o[4] = f2bf(b.x); o[5] = f2bf(b.y); o[6] = f2bf(b.z); o[7] = f2bf(b.w);
    *(u16x8*)(xb + i * 8) = o;
}

// ---- 256x256 GEMM, merged 2-phase schedule (2 barriers/tile, was 8) ----
// PA: 32 MFMA (m03 x n0123); PB: 32 MFMA (m47 x n0123).
// Race ledger (stage R(tt+2) >= 1 barrier after all-waves drain of R(tt) reads):
//   A47(tt+1) staged at PA: a47(tt-1) readers drained PB(tt-1) lgkm(0),
//     proven by PB(tt-1) mid-barrier.
//   B01/A03/B23(tt+2) staged at PB: their (tt) readers drained at PA's
//     lgkm(4)/lgkm(0), proven by PA-end barrier.
// Landing proof: vmcnt(6) at PB (outstanding = A47(tt+1)x2 + 6 new) drains
//   ALL of tile tt+1; barrier; then tail reads of (tt+1) operands.
// Reg reuse (WAR) orders the post-MFMA reads after their clusters.

#define STAGE_R(sarr, larr, base, kt) do { _Pragma("unroll") \
    for (int j_ = 0; j_ < 2; ++j_) \
        __builtin_amdgcn_global_load_lds( \
            (__attribute__((address_space(1))) u32*)(sarr[j_] + (kt) * 64), \
            (__attribute__((address_space(3))) u32*)(smem + (base) + larr[j_]), \
            16, 0, 0); } while (0)

#define MFMA(d, va, vb) d = __builtin_amdgcn_mfma_f32_16x16x32_bf16(va, vb, d, 0, 0, 0)

__global__ __launch_bounds__(512, 2) void gemm_bt_kernel(const u16* __restrict__ Xb,
                                                         const u16* __restrict__ Wb,
                                                         const float* __restrict__ bias,
                                                         float* __restrict__ out) {
    extern __shared__ __align__(16) char smem[];   // 131072 B
    const int K = D_IN, N = D_OUT;

    int bid = blockIdx.x;                  // 512 blocks
    int swz = (bid & 7) * 64 + (bid >> 3); // XCD swizzle, bijective (512 % 8 == 0)
    int tM = swz >> 4;                     // 32 M-tiles
    int tN = swz & 15;                     // 16 N-tiles

    int t = threadIdx.x;
    int lane = t & 63;
    int wave = t >> 6;
    int wm = wave >> 2;                    // 0..1
    int wn = wave & 3;                     // 0..3
    int lr = lane & 15;
    int hi = lane >> 4;
    int l7 = lane & 7;

    // ds_read byte offsets: row*128 + swizzled 16B slot (slot ^= row&7).
    int xs0 = ((0 * 4 + hi) ^ l7) << 4;    // ks=0
    int xs1 = ((1 * 4 + hi) ^ l7) << 4;    // ks=1
    int aRow = (wm * 128 + lr) * 128;      // + mf*2048
    int bRow = (wn * 64 + lr) * 128;       // + nf*2048

    // Staging: 4 regions x 2 rounds; thread t handles chunk j*512+t of each.
    // Regions (rows): A03={0-63,128-191} A47=+64  B01={0-31,64-95,128-159,192-223} B23=+32
    // LDS dest linear (row*128+slot*16); global source slot pre-XORed (rule 21).
    const u16 *srcA03[2], *srcA47[2], *srcB01[2], *srcB23[2];
    int ldsA03[2], ldsA47[2], ldsB01[2], ldsB23[2];
    #pragma unroll
    for (int j = 0; j < 2; ++j) {
        int idx = j * 512 + t;
        int rl = idx >> 3, slot = idx & 7;
        int rA = (rl & 63) + ((rl >> 6) << 7);
        int rB = (rl & 31) + ((rl >> 5) << 6);
        int r = rA;
        ldsA03[j] = r * 128 + slot * 16;
        srcA03[j] = Xb + (size_t)(tM * 256 + r) * K + ((slot ^ (r & 7)) << 3);
        r = rA + 64;
        ldsA47[j] = r * 128 + slot * 16;
        srcA47[j] = Xb + (size_t)(tM * 256 + r) * K + ((slot ^ (r & 7)) << 3);
        r = rB;
        ldsB01[j] = r * 128 + slot * 16;
        srcB01[j] = Wb + (size_t)(tN * 256 + r) * K + ((slot ^ (r & 7)) << 3);
        r = rB + 32;
        ldsB23[j] = r * 128 + slot * 16;
        srcB23[j] = Wb + (size_t)(tN * 256 + r) * K + ((slot ^ (r & 7)) << 3);
    }

    f32x4 acc[8][4];
    #pragma unroll
    for (int i = 0; i < 8; ++i)
        #pragma unroll
        for (int j = 0; j < 4; ++j)
            acc[i][j] = (f32x4){0.f, 0.f, 0.f, 0.f};

    // prologue: stage tile0 (8 loads) then tile1 minus A47 (6 loads);
    // vmcnt(6) drains tile0; barrier; pre-read tile0 b01/a03/b23.
    STAGE_R(srcA03, ldsA03, 0, 0);     STAGE_R(srcA47, ldsA47, 0, 0);
    STAGE_R(srcB01, ldsB01, 65536, 0); STAGE_R(srcB23, ldsB23, 65536, 0);
    STAGE_R(srcB01, ldsB01, 98304, 1); STAGE_R(srcA03, ldsA03, 32768, 1);
    STAGE_R(srcB23, ldsB23, 98304, 1);
    asm volatile("s_waitcnt vmcnt(6)" ::: "memory");
    __builtin_amdgcn_s_barrier();

    bf16x8 a[4][2], b23[2][2], b01[2][2];
    #pragma unroll
    for (int nf = 0; nf < 2; ++nf) {
        b01[nf][0] = *(const bf16x8*)(smem + 65536 + bRow + nf * 2048 + xs0);
        b01[nf][1] = *(const bf16x8*)(smem + 65536 + bRow + nf * 2048 + xs1);
    }
    #pragma unroll
    for (int mf = 0; mf < 4; ++mf) {
        a[mf][0] = *(const bf16x8*)(smem + aRow + mf * 2048 + xs0);
        a[mf][1] = *(const bf16x8*)(smem + aRow + mf * 2048 + xs1);
    }
    #pragma unroll
    for (int nf = 0; nf < 2; ++nf) {
        b23[nf][0] = *(const bf16x8*)(smem + 65536 + bRow + (nf + 2) * 2048 + xs0);
        b23[nf][1] = *(const bf16x8*)(smem + 65536 + bRow + (nf + 2) * 2048 + xs1);
    }

    for (int tt = 0; tt < NT; ++tt) {
        int pA = (tt & 1) * 32768;
        int pB = 65536 + (tt & 1) * 32768;
        int pAn = ((~tt) & 1) * 32768;
        int pBn = 65536 + ((~tt) & 1) * 32768;

        // ======== PA: stage A47(tt+1); MFMA m03 x {n01, n23}; read a47(tt)
        if (tt + 1 < NT) { STAGE_R(srcA47, ldsA47, pAn, tt + 1); }
        asm volatile("s_waitcnt lgkmcnt(4)");    // FIFO b01(4),a03(8),b23(4): b23 floats
        __builtin_amdgcn_s_setprio(1);
        #pragma unroll
        for (int mf = 0; mf < 4; ++mf)
            #pragma unroll
            for (int nf = 0; nf < 2; ++nf) {
                MFMA(acc[mf][nf], a[mf][0], b01[nf][0]);
                MFMA(acc[mf][nf], a[mf][1], b01[nf][1]);
            }
        asm volatile("s_waitcnt lgkmcnt(0)");    // b23 landed
        #pragma unroll
        for (int mf = 0; mf < 4; ++mf)
            #pragma unroll
            for (int nf = 0; nf < 2; ++nf) {
                MFMA(acc[mf][nf + 2], a[mf][0], b23[nf][0]);
                MFMA(acc[mf][nf + 2], a[mf][1], b23[nf][1]);
            }
        __builtin_amdgcn_s_setprio(0);
        #pragma unroll
        for (int mf = 0; mf < 4; ++mf) {         // a-regs dead -> read a47(tt)
            a[mf][0] = *(const bf16x8*)(smem + pA + aRow + (mf + 4) * 2048 + xs0);
            a[mf][1] = *(const bf16x8*)(smem + pA + aRow + (mf + 4) * 2048 + xs1);
        }
        __builtin_amdgcn_s_barrier();            // PA-end

        // ======== PB: stage B01/A03/B23(tt+2); MFMA m47 x {n01, n23};
        //          vmcnt(6) [tile tt+1 fully landed]; barrier; tail reads (tt+1)
        if (tt + 2 < NT) {
            STAGE_R(srcB01, ldsB01, pB, tt + 2);
            STAGE_R(srcA03, ldsA03, pA, tt + 2);
            STAGE_R(srcB23, ldsB23, pB, tt + 2);
        }
        asm volatile("s_waitcnt lgkmcnt(0)");    // a47(tt) landed
        __builtin_amdgcn_s_setprio(1);
        #pragma unroll
        for (int mf = 0; mf < 4; ++mf)
            #pragma unroll
            for (int nf = 0; nf < 2; ++nf) {
                MFMA(acc[mf + 4][nf], a[mf][0], b01[nf][0]);
                MFMA(acc[mf + 4][nf], a[mf][1], b01[nf][1]);
            }
        #pragma unroll
        for (int mf = 0; mf < 4; ++mf)
            #pragma unroll
            for (int nf = 0; nf < 2; ++nf) {
                MFMA(acc[mf + 4][nf + 2], a[mf][0], b23[nf][0]);
                MFMA(acc[mf + 4][nf + 2], a[mf][1], b23[nf][1]);
            }
        __builtin_amdgcn_s_setprio(0);
        if (tt < NT - 2) { asm volatile("s_waitcnt vmcnt(6)" ::: "memory"); }
        else             { asm volatile("s_waitcnt vmcnt(0)" ::: "memory"); }
        __builtin_amdgcn_s_barrier();            // PB-mid: tile tt+1 visible to all
        if (tt + 1 < NT) {
            #pragma unroll
            for (int nf = 0; nf < 2; ++nf) {     // b01 dead -> b01(tt+1)
                b01[nf][0] = *(const bf16x8*)(smem + pBn + bRow + nf * 2048 + xs0);
                b01[nf][1] = *(const bf16x8*)(smem + pBn + bRow + nf * 2048 + xs1);
            }
            #pragma unroll
            for (int mf = 0; mf < 4; ++mf) {     // a dead -> a03(tt+1)
                a[mf][0] = *(const bf16x8*)(smem + pAn + aRow + mf * 2048 + xs0);
                a[mf][1] = *(const bf16x8*)(smem + pAn + aRow + mf * 2048 + xs1);
            }
            #pragma unroll
            for (int nf = 0; nf < 2; ++nf) {     // b23 dead -> b23(tt+1)
                b23[nf][0] = *(const bf16x8*)(smem + pBn + bRow + (nf + 2) * 2048 + xs0);
                b23[nf][1] = *(const bf16x8*)(smem + pBn + bRow + (nf + 2) * 2048 + xs1);
            }
        }
    }

    // epilogue: C/D layout col=lane&15, row=(lane>>4)*4+reg
    #pragma unroll
    for (int nf = 0; nf < 4; ++nf) {
        int gn = tN * 256 + wn * 64 + nf * 16 + lr;
        float bs = bias[gn];
        #pragma unroll
        for (int mf = 0; mf < 8; ++mf) {
            #pragma unroll
            for (int r = 0; r < 4; ++r) {
                int gm = tM * 256 + wm * 128 + mf * 16 + hi * 4 + r;
                out[(size_t)gm * N + gn] = acc[mf][nf][r] + bs;
            }
        }
    }
}

extern "C" void kernel_launch(void* const* d_in, const int* in_sizes, int n_in,
                              void* d_out, int out_size, void* d_ws, size_t ws_size,
                              hipStream_t stream) {
    (void)in_sizes; (void)n_in; (void)out_size; (void)ws_size;
    const float* x      = (const float*)d_in[0];
    const int*   qw     = (const int*)d_in[1];
    const float* wmin   = (const float*)d_in[2];
    const float* wscale = (const float*)d_in[3];
    const float* bias   = (const float*)d_in[4];
    const float* A      = (const float*)d_in[5];
    const float* Bm     = (const float*)d_in[6];
    float* out = (float*)d_out;

    u16* Wb = (u16*)d_ws;                         // 4096*4096*2 = 33.5 MB
    u16* Xb = Wb + (size_t)D_OUT * D_IN;          // 8192*4096*2 = 67.1 MB

    dequant_fold_kernel<<<D_OUT / OPB, 256, 0, stream>>>(qw, wmin, wscale, A, Bm, Wb);
    xcast_kernel<<<(M_TOT * D_IN) / (256 * 8), 256, 0, stream>>>(x, Xb);
    gemm_bt_kernel<<<(M_TOT / BM) * (D_OUT / BN), 512, 131072, stream>>>(Xb, Wb, bias, out);
}

// Round 12
// 283.779 us; speedup vs baseline: 1.0113x; 1.0113x over previous
//
#include <hip/hip_runtime.h>
#include <hip/hip_bf16.h>

typedef unsigned short u16;
typedef unsigned int u32;
typedef __bf16 bf16x8 __attribute__((ext_vector_type(8)));
typedef float f32x4 __attribute__((ext_vector_type(4)));
typedef int i32x4 __attribute__((ext_vector_type(4)));
typedef u16 u16x4 __attribute__((ext_vector_type(4)));
typedef u16 u16x8 __attribute__((ext_vector_type(8)));

#define D_IN 4096
#define D_OUT 4096
#define M_TOT 8192
#define RANK_ 16

#define BM 256
#define BN 256
#define BK 64
#define NT (D_IN / BK)   // 64 K-tiles
#define OPB 2            // dequant rows per block
#define DQ_BLOCKS (D_OUT / OPB)                      // 2048
#define XC_BLOCKS ((M_TOT * D_IN) / (256 * 8))       // 16384

__device__ __forceinline__ u16 f2bf(float f) {
    union { float f; u32 u; } v; v.f = f;
    u32 u = v.u;
    u32 r = (u + 0x7FFFu + ((u >> 16) & 1u)) >> 16;  // round-to-nearest-even
    return (u16)r;
}

// Fused producer: blocks [0,2048) dequant+fold, [2048, 18432) x-cast.
// Both memory-bound; fusing removes a launch gap and overlaps tails.
__global__ __launch_bounds__(256) void producer_kernel(
        const int* __restrict__ q, const float* __restrict__ wmin,
        const float* __restrict__ wscale, const float* __restrict__ A,
        const float* __restrict__ Bm, const float* __restrict__ x,
        u16* __restrict__ Wb, u16* __restrict__ Xb) {
    const int K = D_IN;
    if (blockIdx.x < DQ_BLOCKS) {
        // W_eff[o,i] = q[o,i]*scale[o] + min[o] + 2*sum_r B[o,r]*A[r,i] -> bf16
        int o0 = blockIdx.x * OPB;
        float s0 = wscale[o0], s1 = wscale[o0 + 1];
        float m0 = wmin[o0],   m1 = wmin[o0 + 1];
        float Br0[RANK_], Br1[RANK_];   // block-uniform -> SGPRs
        #pragma unroll
        for (int r = 0; r < RANK_; ++r) {
            Br0[r] = 2.0f * Bm[(size_t)o0 * RANK_ + r];
            Br1[r] = 2.0f * Bm[(size_t)(o0 + 1) * RANK_ + r];
        }
        for (int i4 = threadIdx.x; i4 < K / 4; i4 += 256) {
            int i = i4 * 4;
            i32x4 q0 = __builtin_nontemporal_load((const i32x4*)(q + (size_t)o0 * K + i));
            i32x4 q1 = __builtin_nontemporal_load((const i32x4*)(q + (size_t)(o0 + 1) * K + i));
            float v00 = (float)q0.x * s0 + m0, v01 = (float)q0.y * s0 + m0;
            float v02 = (float)q0.z * s0 + m0, v03 = (float)q0.w * s0 + m0;
            float v10 = (float)q1.x * s1 + m1, v11 = (float)q1.y * s1 + m1;
            float v12 = (float)q1.z * s1 + m1, v13 = (float)q1.w * s1 + m1;
            #pragma unroll
            for (int r = 0; r < RANK_; ++r) {
                f32x4 av = *(const f32x4*)(A + (size_t)r * K + i);
                v00 += Br0[r] * av.x; v01 += Br0[r] * av.y;
                v02 += Br0[r] * av.z; v03 += Br0[r] * av.w;
                v10 += Br1[r] * av.x; v11 += Br1[r] * av.y;
                v12 += Br1[r] * av.z; v13 += Br1[r] * av.w;
            }
            u16x4 o0v, o1v;
            o0v.x = f2bf(v00); o0v.y = f2bf(v01); o0v.z = f2bf(v02); o0v.w = f2bf(v03);
            o1v.x = f2bf(v10); o1v.y = f2bf(v11); o1v.z = f2bf(v12); o1v.w = f2bf(v13);
            *(u16x4*)(Wb + (size_t)o0 * K + i) = o0v;
            *(u16x4*)(Wb + (size_t)(o0 + 1) * K + i) = o1v;
        }
    } else {
        // fp32 -> bf16, 8 elems/thread
        size_t i = (size_t)(blockIdx.x - DQ_BLOCKS) * 256 + threadIdx.x;
        const f32x4* p = (const f32x4*)x + i * 2;
        f32x4 a = __builtin_nontemporal_load(p);
        f32x4 b = __builtin_nontemporal_load(p + 1);
        u16x8 o;
        o[0] = f2bf(a.x); o[1] = f2bf(a.y); o[2] = f2bf(a.z); o[3] = f2bf(a.w);
        o[4] = f2bf(b.x); o[5] = f2bf(b.y); o[6] = f2bf(b.z); o[7] = f2bf(b.w);
        *(u16x8*)(Xb + i * 8) = o;
    }
}

// ---- 256x256 GEMM, 2-phase with shadowed waits ----
// PA: 32 MFMA (m03 x n0123); PB: 32 MFMA (m47 x n0123).
// PB order: stage 6 of (tt+2); vmcnt(6) [ledger: 6x(tt+1)@PB(tt-1) +
//   2xA47(tt+1)@PA(tt) + 6x(tt+2) = 14 -> drains all of tt+1; A47(tt+1)
//   had full PA duration in flight]; barrier; lgkm(0) [a47(tt), shadowed by
//   stage+vmcnt+barrier]; cluster1(n01); read b01(tt+1) [b01 dead, tt+1
//   landed]; cluster2(n23) hides them; tail-read a03/b23(tt+1); barrier.
// PA: stage A47(tt+1) [region-safe: a47(tt-1) drained at PB(tt-1) lgkm(0),
//   PB-end barrier passed]; lgkm(4) [FIFO b01,a03,b23: b23 floats];
//   cluster1(n01); lgkm(0); cluster2(n23); read a47(tt); barrier.

#define STAGE_R(sarr, larr, base, kt) do { _Pragma("unroll") \
    for (int j_ = 0; j_ < 2; ++j_) \
        __builtin_amdgcn_global_load_lds( \
            (__attribute__((address_space(1))) u32*)(sarr[j_] + (kt) * 64), \
            (__attribute__((address_space(3))) u32*)(smem + (base) + larr[j_]), \
            16, 0, 0); } while (0)

#define MFMA(d, va, vb) d = __builtin_amdgcn_mfma_f32_16x16x32_bf16(va, vb, d, 0, 0, 0)

__global__ __launch_bounds__(512, 2) void gemm_bt_kernel(const u16* __restrict__ Xb,
                                                         const u16* __restrict__ Wb,
                                                         const float* __restrict__ bias,
                                                         float* __restrict__ out) {
    extern __shared__ __align__(16) char smem[];   // 131072 B
    const int K = D_IN, N = D_OUT;

    int bid = blockIdx.x;                  // 512 blocks
    int swz = (bid & 7) * 64 + (bid >> 3); // XCD swizzle, bijective (512 % 8 == 0)
    int tM = swz >> 4;                     // 32 M-tiles
    int tN = swz & 15;                     // 16 N-tiles

    int t = threadIdx.x;
    int lane = t & 63;
    int wave = t >> 6;
    int wm = wave >> 2;                    // 0..1
    int wn = wave & 3;                     // 0..3
    int lr = lane & 15;
    int hi = lane >> 4;
    int l7 = lane & 7;

    // ds_read byte offsets: row*128 + swizzled 16B slot (slot ^= row&7).
    int xs0 = ((0 * 4 + hi) ^ l7) << 4;    // ks=0
    int xs1 = ((1 * 4 + hi) ^ l7) << 4;    // ks=1
    int aRow = (wm * 128 + lr) * 128;      // + mf*2048
    int bRow = (wn * 64 + lr) * 128;       // + nf*2048

    // Staging: 4 regions x 2 rounds; thread t handles chunk j*512+t of each.
    // Regions (rows): A03={0-63,128-191} A47=+64  B01={0-31,64-95,128-159,192-223} B23=+32
    // LDS dest linear (row*128+slot*16); global source slot pre-XORed (rule 21).
    const u16 *srcA03[2], *srcA47[2], *srcB01[2], *srcB23[2];
    int ldsA03[2], ldsA47[2], ldsB01[2], ldsB23[2];
    #pragma unroll
    for (int j = 0; j < 2; ++j) {
        int idx = j * 512 + t;
        int rl = idx >> 3, slot = idx & 7;
        int rA = (rl & 63) + ((rl >> 6) << 7);
        int rB = (rl & 31) + ((rl >> 5) << 6);
        int r = rA;
        ldsA03[j] = r * 128 + slot * 16;
        srcA03[j] = Xb + (size_t)(tM * 256 + r) * K + ((slot ^ (r & 7)) << 3);
        r = rA + 64;
        ldsA47[j] = r * 128 + slot * 16;
        srcA47[j] = Xb + (size_t)(tM * 256 + r) * K + ((slot ^ (r & 7)) << 3);
        r = rB;
        ldsB01[j] = r * 128 + slot * 16;
        srcB01[j] = Wb + (size_t)(tN * 256 + r) * K + ((slot ^ (r & 7)) << 3);
        r = rB + 32;
        ldsB23[j] = r * 128 + slot * 16;
        srcB23[j] = Wb + (size_t)(tN * 256 + r) * K + ((slot ^ (r & 7)) << 3);
    }

    f32x4 acc[8][4];
    #pragma unroll
    for (int i = 0; i < 8; ++i)
        #pragma unroll
        for (int j = 0; j < 4; ++j)
            acc[i][j] = (f32x4){0.f, 0.f, 0.f, 0.f};

    // prologue: stage tile0 (8) + tile1 minus A47 (6); vmcnt(6) drains tile0;
    // barrier; pre-read tile0 b01/a03/b23.
    STAGE_R(srcA03, ldsA03, 0, 0);     STAGE_R(srcA47, ldsA47, 0, 0);
    STAGE_R(srcB01, ldsB01, 65536, 0); STAGE_R(srcB23, ldsB23, 65536, 0);
    STAGE_R(srcB01, ldsB01, 98304, 1); STAGE_R(srcA03, ldsA03, 32768, 1);
    STAGE_R(srcB23, ldsB23, 98304, 1);
    asm volatile("s_waitcnt vmcnt(6)" ::: "memory");
    __builtin_amdgcn_s_barrier();

    bf16x8 a[4][2], b23[2][2], b01[2][2];
    #pragma unroll
    for (int nf = 0; nf < 2; ++nf) {
        b01[nf][0] = *(const bf16x8*)(smem + 65536 + bRow + nf * 2048 + xs0);
        b01[nf][1] = *(const bf16x8*)(smem + 65536 + bRow + nf * 2048 + xs1);
    }
    #pragma unroll
    for (int mf = 0; mf < 4; ++mf) {
        a[mf][0] = *(const bf16x8*)(smem + aRow + mf * 2048 + xs0);
        a[mf][1] = *(const bf16x8*)(smem + aRow + mf * 2048 + xs1);
    }
    #pragma unroll
    for (int nf = 0; nf < 2; ++nf) {
        b23[nf][0] = *(const bf16x8*)(smem + 65536 + bRow + (nf + 2) * 2048 + xs0);
        b23[nf][1] = *(const bf16x8*)(smem + 65536 + bRow + (nf + 2) * 2048 + xs1);
    }

    for (int tt = 0; tt < NT; ++tt) {
        int pA = (tt & 1) * 32768;
        int pB = 65536 + (tt & 1) * 32768;
        int pAn = ((~tt) & 1) * 32768;
        int pBn = 65536 + ((~tt) & 1) * 32768;

        // ======== PA: stage A47(tt+1); MFMA m03 x {n01, n23}; read a47(tt)
        if (tt + 1 < NT) { STAGE_R(srcA47, ldsA47, pAn, tt + 1); }
        asm volatile("s_waitcnt lgkmcnt(4)");    // FIFO b01(4),a03(8),b23(4): b23 floats
        __builtin_amdgcn_s_setprio(1);
        #pragma unroll
        for (int mf = 0; mf < 4; ++mf)
            #pragma unroll
            for (int nf = 0; nf < 2; ++nf) {
                MFMA(acc[mf][nf], a[mf][0], b01[nf][0]);
                MFMA(acc[mf][nf], a[mf][1], b01[nf][1]);
            }
        asm volatile("s_waitcnt lgkmcnt(0)");    // b23 landed
        #pragma unroll
        for (int mf = 0; mf < 4; ++mf)
            #pragma unroll
            for (int nf = 0; nf < 2; ++nf) {
                MFMA(acc[mf][nf + 2], a[mf][0], b23[nf][0]);
                MFMA(acc[mf][nf + 2], a[mf][1], b23[nf][1]);
            }
        __builtin_amdgcn_s_setprio(0);
        #pragma unroll
        for (int mf = 0; mf < 4; ++mf) {         // a-regs dead -> read a47(tt)
            a[mf][0] = *(const bf16x8*)(smem + pA + aRow + (mf + 4) * 2048 + xs0);
            a[mf][1] = *(const bf16x8*)(smem + pA + aRow + (mf + 4) * 2048 + xs1);
        }
        __builtin_amdgcn_s_barrier();            // PA-end

        // ======== PB: stage 6 of (tt+2); vmcnt(6); barrier; clusters with
        //          b01(tt+1) read hidden between them; tail a03/b23(tt+1).
        if (tt + 2 < NT) {
            STAGE_R(srcB01, ldsB01, pB, tt + 2);
            STAGE_R(srcA03, ldsA03, pA, tt + 2);
            STAGE_R(srcB23, ldsB23, pB, tt + 2);
        }
        if (tt < NT - 2) { asm volatile("s_waitcnt vmcnt(6)" ::: "memory"); }
        else             { asm volatile("s_waitcnt vmcnt(0)" ::: "memory"); }
        __builtin_amdgcn_s_barrier();            // tile tt+1 visible to all
        asm volatile("s_waitcnt lgkmcnt(0)");    // a47(tt): shadowed by stage+vmcnt+bar
        __builtin_amdgcn_s_setprio(1);
        #pragma unroll
        for (int mf = 0; mf < 4; ++mf)
            #pragma unroll
            for (int nf = 0; nf < 2; ++nf) {
                MFMA(acc[mf + 4][nf], a[mf][0], b01[nf][0]);
                MFMA(acc[mf + 4][nf], a[mf][1], b01[nf][1]);
            }
        if (tt + 1 < NT) {
            #pragma unroll
            for (int nf = 0; nf < 2; ++nf) {     // b01 dead -> b01(tt+1); hidden by cl2
                b01[nf][0] = *(const bf16x8*)(smem + pBn + bRow + nf * 2048 + xs0);
                b01[nf][1] = *(const bf16x8*)(smem + pBn + bRow + nf * 2048 + xs1);
            }
        }
        #pragma unroll
        for (int mf = 0; mf < 4; ++mf)
            #pragma unroll
            for (int nf = 0; nf < 2; ++nf) {
                MFMA(acc[mf + 4][nf + 2], a[mf][0], b23[nf][0]);
                MFMA(acc[mf + 4][nf + 2], a[mf][1], b23[nf][1]);
            }
        __builtin_amdgcn_s_setprio(0);
        if (tt + 1 < NT) {
            #pragma unroll
            for (int mf = 0; mf < 4; ++mf) {     // a dead -> a03(tt+1)
                a[mf][0] = *(const bf16x8*)(smem + pAn + aRow + mf * 2048 + xs0);
                a[mf][1] = *(const bf16x8*)(smem + pAn + aRow + mf * 2048 + xs1);
            }
            #pragma unroll
            for (int nf = 0; nf < 2; ++nf) {     // b23 dead -> b23(tt+1)
                b23[nf][0] = *(const bf16x8*)(smem + pBn + bRow + (nf + 2) * 2048 + xs0);
                b23[nf][1] = *(const bf16x8*)(smem + pBn + bRow + (nf + 2) * 2048 + xs1);
            }
        }
        __builtin_amdgcn_s_barrier();            // PB-end: enables PA(tt+1) A47 stage
    }

    // epilogue: C/D layout col=lane&15, row=(lane>>4)*4+reg
    #pragma unroll
    for (int nf = 0; nf < 4; ++nf) {
        int gn = tN * 256 + wn * 64 + nf * 16 + lr;
        float bs = bias[gn];
        #pragma unroll
        for (int mf = 0; mf < 8; ++mf) {
            #pragma unroll
            for (int r = 0; r < 4; ++r) {
                int gm = tM * 256 + wm * 128 + mf * 16 + hi * 4 + r;
                out[(size_t)gm * N + gn] = acc[mf][nf][r] + bs;
            }
        }
    }
}

extern "C" void kernel_launch(void* const* d_in, const int* in_sizes, int n_in,
                              void* d_out, int out_size, void* d_ws, size_t ws_size,
                              hipStream_t stream) {
    (void)in_sizes; (void)n_in; (void)out_size; (void)ws_size;
    const float* x      = (const float*)d_in[0];
    const int*   qw     = (const int*)d_in[1];
    const float* wmin   = (const float*)d_in[2];
    const float* wscale = (const float*)d_in[3];
    const float* bias   = (const float*)d_in[4];
    const float* A      = (const float*)d_in[5];
    const float* Bm     = (const float*)d_in[6];
    float* out = (float*)d_out;

    u16* Wb = (u16*)d_ws;                         // 4096*4096*2 = 33.5 MB
    u16* Xb = Wb + (size_t)D_OUT * D_IN;          // 8192*4096*2 = 67.1 MB

    producer_kernel<<<DQ_BLOCKS + XC_BLOCKS, 256, 0, stream>>>(
        qw, wmin, wscale, A, Bm, x, Wb, Xb);
    gemm_bt_kernel<<<(M_TOT / BM) * (D_OUT / BN), 512, 131072, stream>>>(Xb, Wb, bias, out);
}

// Round 13
// 275.752 us; speedup vs baseline: 1.0408x; 1.0291x over previous
//
#include <hip/hip_runtime.h>
#include <hip/hip_bf16.h>

typedef unsigned short u16;
typedef unsigned int u32;
typedef __bf16 bf16x8 __attribute__((ext_vector_type(8)));
typedef float f32x4 __attribute__((ext_vector_type(4)));
typedef int i32x4 __attribute__((ext_vector_type(4)));
typedef u16 u16x4 __attribute__((ext_vector_type(4)));
typedef u16 u16x8 __attribute__((ext_vector_type(8)));

#define D_IN 4096
#define D_OUT 4096
#define M_TOT 8192
#define RANK_ 16

#define BM 256
#define BN 256
#define BK 64
#define NT (D_IN / BK)   // 64 K-tiles
#define OPB 2            // dequant rows per block
#define DQ_BLOCKS (D_OUT / OPB)                      // 2048
#define XC_BLOCKS ((M_TOT * D_IN) / (256 * 8))       // 16384

__device__ __forceinline__ u16 f2bf(float f) {
    union { float f; u32 u; } v; v.f = f;
    u32 u = v.u;
    u32 r = (u + 0x7FFFu + ((u >> 16) & 1u)) >> 16;  // round-to-nearest-even
    return (u16)r;
}

// Fused producer: blocks [0,2048) dequant+fold, [2048, 18432) x-cast.
__global__ __launch_bounds__(256) void producer_kernel(
        const int* __restrict__ q, const float* __restrict__ wmin,
        const float* __restrict__ wscale, const float* __restrict__ A,
        const float* __restrict__ Bm, const float* __restrict__ x,
        u16* __restrict__ Wb, u16* __restrict__ Xb) {
    const int K = D_IN;
    if (blockIdx.x < DQ_BLOCKS) {
        // W_eff[o,i] = q[o,i]*scale[o] + min[o] + 2*sum_r B[o,r]*A[r,i] -> bf16
        int o0 = blockIdx.x * OPB;
        float s0 = wscale[o0], s1 = wscale[o0 + 1];
        float m0 = wmin[o0],   m1 = wmin[o0 + 1];
        float Br0[RANK_], Br1[RANK_];   // block-uniform -> SGPRs
        #pragma unroll
        for (int r = 0; r < RANK_; ++r) {
            Br0[r] = 2.0f * Bm[(size_t)o0 * RANK_ + r];
            Br1[r] = 2.0f * Bm[(size_t)(o0 + 1) * RANK_ + r];
        }
        for (int i4 = threadIdx.x; i4 < K / 4; i4 += 256) {
            int i = i4 * 4;
            i32x4 q0 = __builtin_nontemporal_load((const i32x4*)(q + (size_t)o0 * K + i));
            i32x4 q1 = __builtin_nontemporal_load((const i32x4*)(q + (size_t)(o0 + 1) * K + i));
            float v00 = (float)q0.x * s0 + m0, v01 = (float)q0.y * s0 + m0;
            float v02 = (float)q0.z * s0 + m0, v03 = (float)q0.w * s0 + m0;
            float v10 = (float)q1.x * s1 + m1, v11 = (float)q1.y * s1 + m1;
            float v12 = (float)q1.z * s1 + m1, v13 = (float)q1.w * s1 + m1;
            #pragma unroll
            for (int r = 0; r < RANK_; ++r) {
                f32x4 av = *(const f32x4*)(A + (size_t)r * K + i);
                v00 += Br0[r] * av.x; v01 += Br0[r] * av.y;
                v02 += Br0[r] * av.z; v03 += Br0[r] * av.w;
                v10 += Br1[r] * av.x; v11 += Br1[r] * av.y;
                v12 += Br1[r] * av.z; v13 += Br1[r] * av.w;
            }
            u16x4 o0v, o1v;
            o0v.x = f2bf(v00); o0v.y = f2bf(v01); o0v.z = f2bf(v02); o0v.w = f2bf(v03);
            o1v.x = f2bf(v10); o1v.y = f2bf(v11); o1v.z = f2bf(v12); o1v.w = f2bf(v13);
            *(u16x4*)(Wb + (size_t)o0 * K + i) = o0v;
            *(u16x4*)(Wb + (size_t)(o0 + 1) * K + i) = o1v;
        }
    } else {
        // fp32 -> bf16, 8 elems/thread
        size_t i = (size_t)(blockIdx.x - DQ_BLOCKS) * 256 + threadIdx.x;
        const f32x4* p = (const f32x4*)x + i * 2;
        f32x4 a = __builtin_nontemporal_load(p);
        f32x4 b = __builtin_nontemporal_load(p + 1);
        u16x8 o;
        o[0] = f2bf(a.x); o[1] = f2bf(a.y); o[2] = f2bf(a.z); o[3] = f2bf(a.w);
        o[4] = f2bf(b.x); o[5] = f2bf(b.y); o[6] = f2bf(b.z); o[7] = f2bf(b.w);
        *(u16x8*)(Xb + i * 8) = o;
    }
}

// ---- 256x256 8-phase GEMM, fully rotated reads (R10, measured best) ----
// Quadrant order (m03,n01)(m03,n23)(m47,n01)(m47,n23).
// ALL ds_reads issue in an earlier phase's shadow, zero extra registers:
//   b01(tt+1): P4 pre-MFMA (after vmcnt+barrier; b01 dead after P3)
//   a03(tt+1)+b23(tt+1): P4 post-MFMA (a,b23 dead after P4's MFMA)
//   a47(tt):  P2 post-MFMA (a dead after P2's MFMA; region landed P4(tt-1))
// Pre-MFMA waits: P1 lgkm(4) [FIFO b01,a03,b23 -> b23 floats], P2 lgkm(0)
// [b23 landed under P1 MFMA], P3 lgkm(0) [a47 landed under P2-close], P4 none.
// Staging 2 loads/phase: P1 B01(tt+2), P2 A03, P3 B23, P4 A47;
// vmcnt(8) once per tile (8 newest = tile tt+2 stay in flight).

#define STAGE_R(sarr, larr, base, kt) do { _Pragma("unroll") \
    for (int j_ = 0; j_ < 2; ++j_) \
        __builtin_amdgcn_global_load_lds( \
            (__attribute__((address_space(1))) u32*)(sarr[j_] + (kt) * 64), \
            (__attribute__((address_space(3))) u32*)(smem + (base) + larr[j_]), \
            16, 0, 0); } while (0)

#define MFMA(d, va, vb) d = __builtin_amdgcn_mfma_f32_16x16x32_bf16(va, vb, d, 0, 0, 0)

__global__ __launch_bounds__(512, 2) void gemm_bt_kernel(const u16* __restrict__ Xb,
                                                         const u16* __restrict__ Wb,
                                                         const float* __restrict__ bias,
                                                         float* __restrict__ out) {
    extern __shared__ __align__(16) char smem[];   // 131072 B
    const int K = D_IN, N = D_OUT;

    int bid = blockIdx.x;                  // 512 blocks
    int swz = (bid & 7) * 64 + (bid >> 3); // XCD swizzle, bijective (512 % 8 == 0)
    int tM = swz >> 4;                     // 32 M-tiles
    int tN = swz & 15;                     // 16 N-tiles

    int t = threadIdx.x;
    int lane = t & 63;
    int wave = t >> 6;
    int wm = wave >> 2;                    // 0..1
    int wn = wave & 3;                     // 0..3
    int lr = lane & 15;
    int hi = lane >> 4;
    int l7 = lane & 7;

    // ds_read byte offsets: row*128 + swizzled 16B slot (slot ^= row&7).
    int xs0 = ((0 * 4 + hi) ^ l7) << 4;    // ks=0
    int xs1 = ((1 * 4 + hi) ^ l7) << 4;    // ks=1
    int aRow = (wm * 128 + lr) * 128;      // + mf*2048
    int bRow = (wn * 64 + lr) * 128;       // + nf*2048

    // Staging: 4 regions x 2 rounds; thread t handles chunk j*512+t of each.
    // Regions (rows): A03={0-63,128-191} A47=+64  B01={0-31,64-95,128-159,192-223} B23=+32
    // LDS dest linear (row*128+slot*16); global source slot pre-XORed (rule 21).
    const u16 *srcA03[2], *srcA47[2], *srcB01[2], *srcB23[2];
    int ldsA03[2], ldsA47[2], ldsB01[2], ldsB23[2];
    #pragma unroll
    for (int j = 0; j < 2; ++j) {
        int idx = j * 512 + t;
        int rl = idx >> 3, slot = idx & 7;
        int rA = (rl & 63) + ((rl >> 6) << 7);
        int rB = (rl & 31) + ((rl >> 5) << 6);
        int r = rA;
        ldsA03[j] = r * 128 + slot * 16;
        srcA03[j] = Xb + (size_t)(tM * 256 + r) * K + ((slot ^ (r & 7)) << 3);
        r = rA + 64;
        ldsA47[j] = r * 128 + slot * 16;
        srcA47[j] = Xb + (size_t)(tM * 256 + r) * K + ((slot ^ (r & 7)) << 3);
        r = rB;
        ldsB01[j] = r * 128 + slot * 16;
        srcB01[j] = Wb + (size_t)(tN * 256 + r) * K + ((slot ^ (r & 7)) << 3);
        r = rB + 32;
        ldsB23[j] = r * 128 + slot * 16;
        srcB23[j] = Wb + (size_t)(tN * 256 + r) * K + ((slot ^ (r & 7)) << 3);
    }

    f32x4 acc[8][4];
    #pragma unroll
    for (int i = 0; i < 8; ++i)
        #pragma unroll
        for (int j = 0; j < 4; ++j)
            acc[i][j] = (f32x4){0.f, 0.f, 0.f, 0.f};

    // prologue: stage tile0 -> buf0, tile1 -> buf1; wait tile0;
    // pre-read b01(t0), a03(t0), b23(t0) (the "P4-tail" of a virtual tt=-1)
    STAGE_R(srcA03, ldsA03, 0, 0);     STAGE_R(srcA47, ldsA47, 0, 0);
    STAGE_R(srcB01, ldsB01, 65536, 0); STAGE_R(srcB23, ldsB23, 65536, 0);
    STAGE_R(srcA03, ldsA03, 32768, 1); STAGE_R(srcA47, ldsA47, 32768, 1);
    STAGE_R(srcB01, ldsB01, 98304, 1); STAGE_R(srcB23, ldsB23, 98304, 1);
    asm volatile("s_waitcnt vmcnt(8)" ::: "memory");
    __builtin_amdgcn_s_barrier();

    bf16x8 a[4][2], b23[2][2], b01[2][2];
    #pragma unroll
    for (int nf = 0; nf < 2; ++nf) {
        b01[nf][0] = *(const bf16x8*)(smem + 65536 + bRow + nf * 2048 + xs0);
        b01[nf][1] = *(const bf16x8*)(smem + 65536 + bRow + nf * 2048 + xs1);
    }
    #pragma unroll
    for (int mf = 0; mf < 4; ++mf) {
        a[mf][0] = *(const bf16x8*)(smem + aRow + mf * 2048 + xs0);
        a[mf][1] = *(const bf16x8*)(smem + aRow + mf * 2048 + xs1);
    }
    #pragma unroll
    for (int nf = 0; nf < 2; ++nf) {
        b23[nf][0] = *(const bf16x8*)(smem + 65536 + bRow + (nf + 2) * 2048 + xs0);
        b23[nf][1] = *(const bf16x8*)(smem + 65536 + bRow + (nf + 2) * 2048 + xs1);
    }

    for (int tt = 0; tt < NT; ++tt) {
        int pA = (tt & 1) * 32768;
        int pB = 65536 + (tt & 1) * 32768;
        int pBn = 65536 + ((~tt) & 1) * 32768;
        int pAn = ((~tt) & 1) * 32768;
        bool pre = (tt + 2 < NT);

        // ---- P1: no reads; stage B01(tt+2); MFMA (m03, n01)
        //      lgkm(4): FIFO [b01(4), a03(8), b23(4)] -> b01+a03 done, b23 floats
        if (pre) { STAGE_R(srcB01, ldsB01, pB, tt + 2); }
        __builtin_amdgcn_s_barrier();
        asm volatile("s_waitcnt lgkmcnt(4)");
        __builtin_amdgcn_s_setprio(1);
        #pragma unroll
        for (int mf = 0; mf < 4; ++mf)
            #pragma unroll
            for (int nf = 0; nf < 2; ++nf) {
                MFMA(acc[mf][nf], a[mf][0], b01[nf][0]);
                MFMA(acc[mf][nf], a[mf][1], b01[nf][1]);
            }
        __builtin_amdgcn_s_setprio(0);
        __builtin_amdgcn_s_barrier();

        // ---- P2: stage A03(tt+2); MFMA (m03, n23); post-MFMA read a47(tt)
        if (pre) { STAGE_R(srcA03, ldsA03, pA, tt + 2); }
        __builtin_amdgcn_s_barrier();
        asm volatile("s_waitcnt lgkmcnt(0)");                // b23 landed under P1
        __builtin_amdgcn_s_setprio(1);
        #pragma unroll
        for (int mf = 0; mf < 4; ++mf)
            #pragma unroll
            for (int nf = 0; nf < 2; ++nf) {
                MFMA(acc[mf][nf + 2], a[mf][0], b23[nf][0]);
                MFMA(acc[mf][nf + 2], a[mf][1], b23[nf][1]);
            }
        __builtin_amdgcn_s_setprio(0);
        #pragma unroll
        for (int mf = 0; mf < 4; ++mf) {                     // a-regs dead -> a47
            a[mf][0] = *(const bf16x8*)(smem + pA + aRow + (mf + 4) * 2048 + xs0);
            a[mf][1] = *(const bf16x8*)(smem + pA + aRow + (mf + 4) * 2048 + xs1);
        }
        __builtin_amdgcn_s_barrier();

        // ---- P3: stage B23(tt+2); MFMA (m47, n01) with b01
        if (pre) { STAGE_R(srcB23, ldsB23, pB, tt + 2); }
        __builtin_amdgcn_s_barrier();
        asm volatile("s_waitcnt lgkmcnt(0)");                // a47 landed under close
        __builtin_amdgcn_s_setprio(1);
        #pragma unroll
        for (int mf = 0; mf < 4; ++mf)
            #pragma unroll
            for (int nf = 0; nf < 2; ++nf) {
                MFMA(acc[mf + 4][nf], a[mf][0], b01[nf][0]);
                MFMA(acc[mf + 4][nf], a[mf][1], b01[nf][1]);
            }
        __builtin_amdgcn_s_setprio(0);
        __builtin_amdgcn_s_barrier();

        // ---- P4: stage A47(tt+2); vmcnt; barrier; pre-MFMA read b01(tt+1);
        //          MFMA (m47, n23); post-MFMA read a03(tt+1)+b23(tt+1)
        if (pre) { STAGE_R(srcA47, ldsA47, pA, tt + 2); }
        if (tt < NT - 2) { asm volatile("s_waitcnt vmcnt(8)" ::: "memory"); }
        else             { asm volatile("s_waitcnt vmcnt(0)" ::: "memory"); }
        __builtin_amdgcn_s_barrier();
        if (tt + 1 < NT) {
            #pragma unroll
            for (int nf = 0; nf < 2; ++nf) {                 // b01 dead after P3
                b01[nf][0] = *(const bf16x8*)(smem + pBn + bRow + nf * 2048 + xs0);
                b01[nf][1] = *(const bf16x8*)(smem + pBn + bRow + nf * 2048 + xs1);
            }
        }
        __builtin_amdgcn_s_setprio(1);
        #pragma unroll
        for (int mf = 0; mf < 4; ++mf)
            #pragma unroll
            for (int nf = 0; nf < 2; ++nf) {
                MFMA(acc[mf + 4][nf + 2], a[mf][0], b23[nf][0]);
                MFMA(acc[mf + 4][nf + 2], a[mf][1], b23[nf][1]);
            }
        __builtin_amdgcn_s_setprio(0);
        if (tt + 1 < NT) {
            #pragma unroll
            for (int mf = 0; mf < 4; ++mf) {                 // a-regs dead -> a03(next)
                a[mf][0] = *(const bf16x8*)(smem + pAn + aRow + mf * 2048 + xs0);
                a[mf][1] = *(const bf16x8*)(smem + pAn + aRow + mf * 2048 + xs1);
            }
            #pragma unroll
            for (int nf = 0; nf < 2; ++nf) {                 // b23 dead -> b23(next)
                b23[nf][0] = *(const bf16x8*)(smem + pBn + bRow + (nf + 2) * 2048 + xs0);
                b23[nf][1] = *(const bf16x8*)(smem + pBn + bRow + (nf + 2) * 2048 + xs1);
            }
        }
        __builtin_amdgcn_s_barrier();
    }

    // epilogue: C/D layout col=lane&15, row=(lane>>4)*4+reg
    #pragma unroll
    for (int nf = 0; nf < 4; ++nf) {
        int gn = tN * 256 + wn * 64 + nf * 16 + lr;
        float bs = bias[gn];
        #pragma unroll
        for (int mf = 0; mf < 8; ++mf) {
            #pragma unroll
            for (int r = 0; r < 4; ++r) {
                int gm = tM * 256 + wm * 128 + mf * 16 + hi * 4 + r;
                out[(size_t)gm * N + gn] = acc[mf][nf][r] + bs;
            }
        }
    }
}

extern "C" void kernel_launch(void* const* d_in, const int* in_sizes, int n_in,
                              void* d_out, int out_size, void* d_ws, size_t ws_size,
                              hipStream_t stream) {
    (void)in_sizes; (void)n_in; (void)out_size; (void)ws_size;
    const float* x      = (const float*)d_in[0];
    const int*   qw     = (const int*)d_in[1];
    const float* wmin   = (const float*)d_in[2];
    const float* wscale = (const float*)d_in[3];
    const float* bias   = (const float*)d_in[4];
    const float* A      = (const float*)d_in[5];
    const float* Bm     = (const float*)d_in[6];
    float* out = (float*)d_out;

    u16* Wb = (u16*)d_ws;                         // 4096*4096*2 = 33.5 MB
    u16* Xb = Wb + (size_t)D_OUT * D_IN;          // 8192*4096*2 = 67.1 MB

    producer_kernel<<<DQ_BLOCKS + XC_BLOCKS, 256, 0, stream>>>(
        qw, wmin, wscale, A, Bm, x, Wb, Xb);
    gemm_bt_kernel<<<(M_TOT / BM) * (D_OUT / BN), 512, 131072, stream>>>(Xb, Wb, bias, out);
}